// Round 3
// baseline (271.622 us; speedup 1.0000x reference)
//
#include <hip/hip_runtime.h>
#include <math.h>

// MoE Router V4 (fused, R3-bit-exact): x(16384,2048) fp32, W(128,2048) fp32,
// bias(128) fp32 -> out = [weights(16384,8) | indices(16384,8) as fp32]
//
// R6: fused single-pass router with R3's EXACT summation order.
//  R5 failed on indices only (absmax 39, weights passed) = adjacent-rank swap
//  of near-tied experts caused by changing the logit accumulation grouping
//  (one 64-chunk MFMA chain vs R3's 4 x 16-chunk split-K chains + fp32 adds).
//  Fix: 4 slice accumulators accs[s] (s = chunk/16, statically indexed via
//  unrolled slice loop), combined as ((a0+a1)+a2)+a3 -- bit-identical logits
//  to the R3 kernel that passed, hence bit-identical top-8 selection.
//  - wprep: split W once into 3 bf16 planes in the LDS image layout
//    [chunk][3][128][32] so router_fused stages W via global_load_lds (16B).
//  - router_fused: 256 blocks x 512 thr, 64 tokens/block, full K in-block,
//    double-buffered LDS, one __syncthreads per chunk, x prefetched in regs.
//    Logits -> LDS (stride 130) -> softmax + stable top-8 + L2 norm in-block.

#define NE      128
#define TOKT    64
#define KC      32
#define DMODEL  2048
#define NT      (DMODEL / KC)        // 64 k-chunks
#define CHUNK_SH (3 * NE * KC)       // 12288 shorts per chunk image

typedef __attribute__((ext_vector_type(8))) short short8;
typedef __attribute__((ext_vector_type(4))) short s16x4;
typedef __attribute__((ext_vector_type(4))) float f32x4;

union S4u { short s[4]; s16x4 v; };

// split one fp32 into 3 truncated bf16 planes (exact residuals)
__device__ __forceinline__ void split3(float f, S4u& hi, S4u& mi, S4u& lo, int j) {
  const unsigned u0 = __float_as_uint(f);
  const float hif = __uint_as_float(u0 & 0xFFFF0000u);
  const float r1 = f - hif;                      // exact
  const unsigned u1 = __float_as_uint(r1);
  const float mif = __uint_as_float(u1 & 0xFFFF0000u);
  const float r2 = r1 - mif;                     // exact
  hi.s[j] = (short)(u0 >> 16);
  mi.s[j] = (short)(u1 >> 16);
  lo.s[j] = (short)(__float_as_uint(r2) >> 16);
}

// W planes precompute: wp[chunk][p][e][kk], identical split3 as x path.
__global__ __launch_bounds__(256) void wprep(const float* __restrict__ w,
                                             short* __restrict__ wp) {
  const int gid = blockIdx.x * 256 + threadIdx.x;  // 65536 threads
  const int e = gid >> 9;                          // expert 0..127
  const int g = gid & 511;                         // float4 group in row
  const int k = g << 2;
  const int chunk = k >> 5;
  const int kk = k & 31;
  const f32x4 a = *(const f32x4*)(w + (size_t)e * DMODEL + k);
  S4u hi, mi, lo;
  split3(a[0], hi, mi, lo, 0); split3(a[1], hi, mi, lo, 1);
  split3(a[2], hi, mi, lo, 2); split3(a[3], hi, mi, lo, 3);
  short* base = wp + (size_t)chunk * CHUNK_SH + (size_t)e * KC + kk;
  *(s16x4*)(base)               = hi.v;
  *(s16x4*)(base + NE * KC)     = mi.v;
  *(s16x4*)(base + 2 * NE * KC) = lo.v;
}

__device__ __forceinline__ void gll16(const short* g, short* l) {
  __builtin_amdgcn_global_load_lds(
      (const __attribute__((address_space(1))) void*)g,
      (__attribute__((address_space(3))) void*)l, 16, 0, 0);
}

__global__ __launch_bounds__(512) void router_fused(
    const float* __restrict__ x, const short* __restrict__ wp,
    const float* __restrict__ bias, float* __restrict__ outW,
    float* __restrict__ outI, int N) {
  // double-buffered staging (72 KB) + logits tile (32.5 KB) = 104.5 KB LDS
  __shared__ __align__(16) short xsm[2][3][TOKT][KC];   // 24 KB
  __shared__ __align__(16) short wsm[2][3][NE][KC];     // 48 KB
  __shared__ float L[TOKT][NE + 2];                     // stride 130 floats

  const int tid  = threadIdx.x;
  const int wv   = tid >> 6;        // 0..7
  const int lane = tid & 63;
  const int wm   = wv >> 2;         // token half (0..1)
  const int wn   = wv & 3;          // expert quarter (0..3)
  const int quad = lane >> 4;
  const int l16  = lane & 15;
  const size_t tokBase = (size_t)blockIdx.x * TOKT;

  // x staging: thread -> (row r, 4-float group kq) of the 64x32 chunk
  const int r  = tid >> 3;          // 0..63
  const int kq = tid & 7;           // 0..7
  const float* xg = x + (tokBase + r) * (size_t)DMODEL + kq * 4;

  // 4 slice accumulators (R3 split-K order); ALL indexing compile-time.
  f32x4 accs[4][2][2];
#pragma unroll
  for (int s = 0; s < 4; ++s)
#pragma unroll
    for (int i = 0; i < 2; ++i)
#pragma unroll
      for (int j = 0; j < 2; ++j) accs[s][i][j] = (f32x4)(0.f);

  // ---- staging helpers (buf is a literal at every call site -> constant-folds)
  auto stage_w = [&](int buf, int chunk) {
    const short* gsrc = wp + (size_t)chunk * CHUNK_SH + wv * 512 + lane * 8;
    short* ldst = &wsm[buf][0][0][0] + wv * 512;   // wave-uniform dest
    gll16(gsrc,        ldst);
    gll16(gsrc + 4096, ldst + 4096);
    gll16(gsrc + 8192, ldst + 8192);
  };
  auto stage_x = [&](int buf, f32x4 xr) {
    S4u hi, mi, lo;
    split3(xr[0], hi, mi, lo, 0); split3(xr[1], hi, mi, lo, 1);
    split3(xr[2], hi, mi, lo, 2); split3(xr[3], hi, mi, lo, 3);
    *(s16x4*)&xsm[buf][0][r][kq * 4] = hi.v;
    *(s16x4*)&xsm[buf][1][r][kq * 4] = mi.v;
    *(s16x4*)&xsm[buf][2][r][kq * 4] = lo.v;
  };
  auto compute = [&](int buf, f32x4 (&acc)[2][2]) {
    short8 af[2][3];
#pragma unroll
    for (int mt = 0; mt < 2; ++mt)
#pragma unroll
      for (int p = 0; p < 3; ++p)
        af[mt][p] = *(const short8*)&xsm[buf][p][wm * 32 + mt * 16 + l16][quad * 8];
#pragma unroll
    for (int nt = 0; nt < 2; ++nt) {
      short8 bf[3];
#pragma unroll
      for (int p = 0; p < 3; ++p)
        bf[p] = *(const short8*)&wsm[buf][p][wn * 32 + nt * 16 + l16][quad * 8];
#pragma unroll
      for (int mt = 0; mt < 2; ++mt) {
        f32x4 c = acc[mt][nt];
        c = __builtin_amdgcn_mfma_f32_16x16x32_bf16(af[mt][0], bf[0], c, 0, 0, 0); // x1w1
        c = __builtin_amdgcn_mfma_f32_16x16x32_bf16(af[mt][0], bf[1], c, 0, 0, 0); // x1w2
        c = __builtin_amdgcn_mfma_f32_16x16x32_bf16(af[mt][1], bf[0], c, 0, 0, 0); // x2w1
        c = __builtin_amdgcn_mfma_f32_16x16x32_bf16(af[mt][0], bf[2], c, 0, 0, 0); // x1w3
        c = __builtin_amdgcn_mfma_f32_16x16x32_bf16(af[mt][2], bf[0], c, 0, 0, 0); // x3w1
        c = __builtin_amdgcn_mfma_f32_16x16x32_bf16(af[mt][1], bf[1], c, 0, 0, 0); // x2w2
        acc[mt][nt] = c;
      }
    }
  };

  // ---- prologue: buffer 0 = chunk 0; x chunks 0,1 prefetched in regs
  stage_w(0, 0);
  f32x4 xra = *(const f32x4*)(xg);        // x chunk 0
  f32x4 xrb = *(const f32x4*)(xg + KC);   // x chunk 1
  stage_x(0, xra);
  __syncthreads();

  // ---- main K loop: slice loop unrolled (static accs[s]), chunk loop rolled.
  // Chunk t = s*16+u is even -> buf0; t+1 odd -> buf1; t, t+1 both in slice s.
#pragma unroll
  for (int s = 0; s < 4; ++s) {
#pragma unroll 1
    for (int u = 0; u < 16; u += 2) {
      const int t = s * 16 + u;
      // even body: compute chunk t from buf0, stage chunk t+1 into buf1
      if (t + 1 < NT) stage_w(1, t + 1);
      if (t + 2 < NT) xra = *(const f32x4*)(xg + (t + 2) * KC);
      compute(0, accs[s]);
      if (t + 1 < NT) { stage_x(1, xrb); __syncthreads(); }
      // odd body: compute chunk t+1 from buf1, stage chunk t+2 into buf0
      if (t + 2 < NT) stage_w(0, t + 2);
      if (t + 3 < NT) xrb = *(const f32x4*)(xg + (t + 3) * KC);
      if (t + 1 < NT) compute(1, accs[s]);
      if (t + 2 < NT) { stage_x(0, xra); __syncthreads(); }
    }
  }

  // ---- combine slices in R3's order (((p0+p1)+p2)+p3) and write logits LDS.
  // C/D layout: col(expert)=l16, row(token)=quad*4+reg  (verified in R3)
#pragma unroll
  for (int mt = 0; mt < 2; ++mt)
#pragma unroll
    for (int nt = 0; nt < 2; ++nt)
#pragma unroll
      for (int reg = 0; reg < 4; ++reg) {
        float v = accs[0][mt][nt][reg];
        v += accs[1][mt][nt][reg];
        v += accs[2][mt][nt][reg];
        v += accs[3][mt][nt][reg];
        L[wm * 32 + mt * 16 + quad * 4 + reg][wn * 32 + nt * 16 + l16] = v;
      }
  __syncthreads();

  // ---- softmax + top-8 + L2 normalize (verified wave-per-token code)
  const float bmy0 = bias[lane];
  const float bmy1 = bias[lane + 64];
  for (int i = 0; i < 8; ++i) {
    const int tk = wv * 8 + i;
    const float l0 = L[tk][lane];
    const float l1 = L[tk][lane + 64];

    float m = fmaxf(l0, l1);
#pragma unroll
    for (int off = 1; off < 64; off <<= 1) m = fmaxf(m, __shfl_xor(m, off));
    const float ev0 = __expf(l0 - m);
    const float ev1 = __expf(l1 - m);
    float zs = ev0 + ev1;
#pragma unroll
    for (int off = 1; off < 64; off <<= 1) zs += __shfl_xor(zs, off);
    const float s0 = ev0 / zs;
    const float s1 = ev1 / zs;

    float b0 = s0 + bmy0;
    float b1 = s1 + bmy1;

    float myv = 0.f;
    int myi = 0;
    float ss = 0.f;
#pragma unroll
    for (int rnd = 0; rnd < 8; ++rnd) {
      float key; int idx;
      if (b0 >= b1) { key = b0; idx = lane; }
      else          { key = b1; idx = lane + 64; }
#pragma unroll
      for (int off = 1; off < 64; off <<= 1) {
        const float k2 = __shfl_xor(key, off);
        const int   i2 = __shfl_xor(idx, off);
        if (k2 > key || (k2 == key && i2 < idx)) { key = k2; idx = i2; }
      }
      const float cand = (idx < 64) ? s0 : s1;
      const float sw = __shfl(cand, idx & 63);
      ss = fmaf(sw, sw, ss);
      if (lane == rnd) { myv = sw; myi = idx; }
      if (lane == (idx & 63)) { if (idx < 64) b0 = -INFINITY; else b1 = -INFINITY; }
    }

    const float inv = 1.f / sqrtf(ss);
    if (lane < 8) {
      const size_t tok = tokBase + tk;
      outW[tok * 8 + lane] = myv * inv;
      outI[tok * 8 + lane] = (float)myi;
    }
  }
}

extern "C" void kernel_launch(void* const* d_in, const int* in_sizes, int n_in,
                              void* d_out, int out_size, void* d_ws, size_t ws_size,
                              hipStream_t stream) {
  const float* x    = (const float*)d_in[0];
  const float* w    = (const float*)d_in[1];
  const float* bias = (const float*)d_in[2];
  float* out = (float*)d_out;

  const int N = in_sizes[0] / DMODEL;  // 16384 tokens
  short* wp = (short*)d_ws;            // 64 chunks * 12288 shorts * 2 B = 1.5 MiB

  wprep<<<256, 256, 0, stream>>>(w, wp);
  router_fused<<<N / TOKT, 512, 0, stream>>>(x, wp, bias, out, out + (size_t)N * 8, N);
}